// Round 2
// baseline (299.903 us; speedup 1.0000x reference)
//
#include <hip/hip_runtime.h>

#define DM 1024
#define HID 64
#define NSTEP 6
#define RSTEP (1.0f/6.0f)

using short8  = __attribute__((ext_vector_type(8))) short;
using short4v = __attribute__((ext_vector_type(4))) short;
using f32x4   = __attribute__((ext_vector_type(4))) float;

// workspace byte offsets
#define WS_W1P 0          // 1024x64 bf16 packed A-frags (131072 B)
#define WS_W2P 131072     // 64x1024 bf16 packed A-frags (131072 B)
#define WS_GP  262144     // 64x64 bf16 packed A-frags (8192 B)
#define WS_U   270336     // 64 f32  (u = b2 @ W1k)

// LDS byte offsets (total 39680 B -> 4 blocks/CU on 160 KiB LDS)
#define L_ZH 0            // [16][1024] bf16 hi of z, XOR-swizzled (32768)
#define L_H0 32768        // H ping  [16][72] bf16, pitch 144 (2304)
#define L_H1 35072        // H pong
#define L_HB 37376        // Hb = (h/6)*Hsum
#define LDS_TOTAL 39680
#define HPITCH 144

__device__ __forceinline__ float bf2f(short s) {
    union { unsigned u; float f; } v;
    v.u = ((unsigned)(unsigned short)s) << 16;
    return v.f;
}
__device__ __forceinline__ short f2bf(float f) {   // round-to-nearest-even
    union { float f; unsigned u; } v;
    v.f = f;
    unsigned u = v.u;
    u += 0x7FFFu + ((u >> 16) & 1u);
    return (short)(u >> 16);
}
__device__ __forceinline__ float ftanh(float x) {
    x = fminf(fmaxf(x, -10.f), 10.f);
    float e = __expf(2.f * x);
    return __fdividef(e - 1.f, e + 1.f);
}

// ---------------- prep: pack weights to MFMA fragment layout ----------------
// A-frag layout for mfma_f32_16x16x32_bf16: lane l holds M-row (l&15),
// k = (l>>4)*8 + i (8 consecutive k). Packed so each lane loads one short8.
__global__ void k_prep(const float* __restrict__ W1, const float* __restrict__ W2,
                       const float* __restrict__ b2,
                       short* __restrict__ W1P, short* __restrict__ W2P,
                       short* __restrict__ GP, float* __restrict__ U) {
    int b = blockIdx.x;
    int l = threadIdx.x;           // 64 threads
    if (b < 128) {                 // W1k (1024x64) -> W1P[kk<32][c<4][l][8]
        int kk = b >> 2, c = b & 3;
        int col = c * 16 + (l & 15);
        int kb = kk * 32 + ((l >> 4) << 3);
        short8 v;
        #pragma unroll
        for (int i = 0; i < 8; ++i) v[i] = f2bf(W1[(kb + i) * HID + col]);
        *(short8*)(W1P + (((kk * 4 + c) * 64) + l) * 8) = v;
    } else if (b < 256) {          // W2 (64x1024) -> W2P[kk2<2][ct<64][l][8]
        int bb = b - 128;
        int kk2 = bb >> 6, ct = bb & 63;
        int col = ct * 16 + (l & 15);
        int kb = kk2 * 32 + ((l >> 4) << 3);
        short8 v;
        #pragma unroll
        for (int i = 0; i < 8; ++i) v[i] = f2bf(W2[(kb + i) * DM + col]);
        *(short8*)(W2P + (((kk2 * 64 + ct) * 64) + l) * 8) = v;
    } else if (b < 320) {          // G[j][i] = sum_d W2[j][d]*W1[d][i]; j = b-256
        int j = b - 256;
        float acc = 0.f;
        #pragma unroll 8
        for (int d = 0; d < DM; ++d) acc += W2[j * DM + d] * W1[d * HID + l];
        int kk = j >> 5, lk = (j >> 3) & 3, ii = j & 7, c = l >> 4, lo = l & 15;
        GP[(((kk * 4 + c) * 64) + lk * 16 + lo) * 8 + ii] = f2bf(acc);
    } else {                       // u[i] = sum_d b2[d]*W1[d][i]
        float acc = 0.f;
        #pragma unroll 8
        for (int d = 0; d < DM; ++d) acc += b2[d] * W1[d * HID + l];
        U[l] = acc;
    }
}

// ---------------- fused RK4 neural-ODE kernel ----------------
// Block: 256 thr (4 waves), owns 16 rows of z for all 6 RK4 steps.
// z master = zh (bf16, LDS, swizzled) + zl (bf16 residual, REGISTERS:
// each lane owns row l15, cols [w*256 + q*16 + hq*4 + j], q=0..15).
// Wave w: GEMM1/stages hid col-tile w (16 cols); GEMM2 cols [w*256,+256).
// MFMA: A = packed weights (M = out-col), B = z/H rows (N = row).
// D: m = (lane>>4)*4+reg (col), n = lane&15 (row).
__global__ __launch_bounds__(256, 4) void k_ode(
        const float* __restrict__ X, const float* __restrict__ W1,
        const float* __restrict__ b1, const float* __restrict__ b2,
        const short* __restrict__ W1P, const short* __restrict__ W2P,
        const short* __restrict__ GP, const float* __restrict__ U,
        float* __restrict__ OUT) {
    extern __shared__ char smem[];
    const int t = threadIdx.x;
    const int lane = t & 63;
    const int w = t >> 6;                    // 0..3
    const int hq = lane >> 4;
    const int l15 = lane & 15;
    const int hcol0 = w * 16 + hq * 4;       // hid-col base (stage epilogues)
    const size_t row0 = (size_t)blockIdx.x * 16;
    const int swl = ((l15 ^ (l15 >> 3)) & 7) << 4;   // row XOR swizzle
    const int zbase = l15 << 11;                      // row byte base in zh

    // per-lane persistent constants (L2-hot broadcasts)
    f32x4 u4   = *(const f32x4*)(U + hcol0);
    f32x4 b14  = *(const f32x4*)(b1 + hcol0);
    f32x4 w1t4 = *(const f32x4*)(W1 + DM * HID + hcol0);   // time row of W1
    short8 gf0 = *(const short8*)(GP + (w * 64 + lane) * 8);
    short8 gf1 = *(const short8*)(GP + ((4 + w) * 64 + lane) * 8);

    // ---- load owned x slice -> zh (LDS) + zl (regs) ----
    short4v zlr[16];
    {
        const float* xrow = X + (row0 + l15) * DM;
        #pragma unroll
        for (int q = 0; q < 16; ++q) {
            int col = w * 256 + q * 16 + hq * 4;
            f32x4 v = *(const f32x4*)(xrow + col);
            short4v hh, ll;
            #pragma unroll
            for (int j = 0; j < 4; ++j) {
                short h = f2bf(v[j]);
                hh[j] = h;
                ll[j] = f2bf(v[j] - bf2f(h));
            }
            zlr[q] = ll;
            *(short4v*)(smem + L_ZH + ((zbase + col * 2) ^ swl)) = hh;
        }
    }
    __syncthreads();

    for (int s = 0; s < NSTEP; ++s) {
        float tcur = RSTEP * (float)s;

        // P1: sz = (z @ W1k) tile; K=1024 in 32 slices, dual accumulators
        f32x4 sz;
        {
            const short8* wp = (const short8*)W1P + (w * 64 + lane);
            f32x4 a0 = (f32x4){0.f, 0.f, 0.f, 0.f};
            f32x4 a1 = (f32x4){0.f, 0.f, 0.f, 0.f};
            #pragma unroll 8
            for (int kk = 0; kk < 32; kk += 2) {
                short8 z0 = *(const short8*)(smem + L_ZH + ((zbase + (kk << 6) + (hq << 4)) ^ swl));
                short8 z1 = *(const short8*)(smem + L_ZH + ((zbase + ((kk + 1) << 6) + (hq << 4)) ^ swl));
                short8 wf0 = wp[kk * 256];
                short8 wf1 = wp[(kk + 1) * 256];
                a0 = __builtin_amdgcn_mfma_f32_16x16x32_bf16(wf0, z0, a0, 0, 0, 0);
                a1 = __builtin_amdgcn_mfma_f32_16x16x32_bf16(wf1, z1, a1, 0, 0, 0);
            }
            sz = a0 + a1;
        }

        // P2: stage 1  H1 = tanh(sz + t*w1t + b1)
        f32x4 hsum;
        {
            short4v hc;
            #pragma unroll
            for (int j = 0; j < 4; ++j) {
                float T = sz[j] + tcur * w1t4[j] + b14[j];
                float h = ftanh(T);
                hsum[j] = h;
                hc[j] = f2bf(h);
            }
            *(short4v*)(smem + L_H0 + l15 * HPITCH + hcol0 * 2) = hc;
        }
        __syncthreads();

        // P3..P5: stages 2..4 via tiny H@G GEMM (G = W2@W1k)
        #pragma unroll
        for (int st = 0; st < 3; ++st) {
            const float c_i = (st == 2) ? RSTEP : (0.5f * RSTEP);
            const float t_i = tcur + ((st == 2) ? RSTEP : (0.5f * RSTEP));
            const float w_i = (st == 2) ? 1.f : 2.f;
            const int rbuf = (st & 1) ? L_H1 : L_H0;
            const int wbuf = (st & 1) ? L_H0 : L_H1;

            f32x4 dd = (f32x4){0.f, 0.f, 0.f, 0.f};
            {
                short8 hf0 = *(const short8*)(smem + rbuf + l15 * HPITCH + (hq << 4));
                short8 hf1 = *(const short8*)(smem + rbuf + l15 * HPITCH + 64 + (hq << 4));
                dd = __builtin_amdgcn_mfma_f32_16x16x32_bf16(gf0, hf0, dd, 0, 0, 0);
                dd = __builtin_amdgcn_mfma_f32_16x16x32_bf16(gf1, hf1, dd, 0, 0, 0);
            }
            short4v hc;
            #pragma unroll
            for (int j = 0; j < 4; ++j) {
                float T = sz[j] + c_i * (dd[j] + u4[j]) + t_i * w1t4[j] + b14[j];
                float h = ftanh(T);
                hsum[j] += w_i * h;
                hc[j] = f2bf(h);
            }
            if (st < 2) {
                *(short4v*)(smem + wbuf + l15 * HPITCH + hcol0 * 2) = hc;
            } else {   // Hb = (h/6) * Hsum, ready as GEMM2 B-operand
                short4v hb4;
                #pragma unroll
                for (int j = 0; j < 4; ++j) hb4[j] = f2bf(hsum[j] * (RSTEP / 6.f));
                *(short4v*)(smem + L_HB + l15 * HPITCH + hcol0 * 2) = hb4;
            }
            __syncthreads();
        }

        // P6: z += Hb @ W2 + h*b2   (wave w owns cols [w*256, w*256+256))
        {
            short8 hb0 = *(const short8*)(smem + L_HB + l15 * HPITCH + (hq << 4));
            short8 hb1 = *(const short8*)(smem + L_HB + l15 * HPITCH + 64 + (hq << 4));
            const short8* w2p8 = (const short8*)W2P;

            if (s < NSTEP - 1) {
                #pragma unroll
                for (int q = 0; q < 16; ++q) {
                    int ct = w * 16 + q;
                    short8 wa = w2p8[ct * 64 + lane];
                    short8 wb = w2p8[(64 + ct) * 64 + lane];
                    f32x4 p = (f32x4){0.f, 0.f, 0.f, 0.f};
                    p = __builtin_amdgcn_mfma_f32_16x16x32_bf16(wa, hb0, p, 0, 0, 0);
                    p = __builtin_amdgcn_mfma_f32_16x16x32_bf16(wb, hb1, p, 0, 0, 0);
                    int colb = w * 512 + q * 32 + hq * 8;   // byte col in zh row
                    int a = (zbase + colb) ^ swl;
                    short4v oh = *(short4v*)(smem + L_ZH + a);
                    f32x4 b2v = *(const f32x4*)(b2 + (colb >> 1));
                    short4v ll = zlr[q], nh, nl;
                    #pragma unroll
                    for (int j = 0; j < 4; ++j) {
                        float v = bf2f(oh[j]) + bf2f(ll[j]) + p[j] + RSTEP * b2v[j];
                        short h = f2bf(v);
                        nh[j] = h;
                        nl[j] = f2bf(v - bf2f(h));
                    }
                    *(short4v*)(smem + L_ZH + a) = nh;
                    zlr[q] = nl;
                }
            } else {   // last step: write final z straight to OUT (f32)
                float* orow = OUT + (row0 + l15) * DM;
                #pragma unroll
                for (int q = 0; q < 16; ++q) {
                    int ct = w * 16 + q;
                    short8 wa = w2p8[ct * 64 + lane];
                    short8 wb = w2p8[(64 + ct) * 64 + lane];
                    f32x4 p = (f32x4){0.f, 0.f, 0.f, 0.f};
                    p = __builtin_amdgcn_mfma_f32_16x16x32_bf16(wa, hb0, p, 0, 0, 0);
                    p = __builtin_amdgcn_mfma_f32_16x16x32_bf16(wb, hb1, p, 0, 0, 0);
                    int colb = w * 512 + q * 32 + hq * 8;
                    int a = (zbase + colb) ^ swl;
                    short4v oh = *(short4v*)(smem + L_ZH + a);
                    f32x4 b2v = *(const f32x4*)(b2 + (colb >> 1));
                    short4v ll = zlr[q];
                    f32x4 v;
                    #pragma unroll
                    for (int j = 0; j < 4; ++j)
                        v[j] = bf2f(oh[j]) + bf2f(ll[j]) + p[j] + RSTEP * b2v[j];
                    *(f32x4*)(orow + (colb >> 1)) = v;
                }
            }
        }
        __syncthreads();
    }
}

extern "C" void kernel_launch(void* const* d_in, const int* in_sizes, int n_in,
                              void* d_out, int out_size, void* d_ws, size_t ws_size,
                              hipStream_t stream) {
    (void)in_sizes; (void)n_in; (void)out_size; (void)ws_size;
    const float* X  = (const float*)d_in[0];
    const float* W1 = (const float*)d_in[1];
    const float* b1 = (const float*)d_in[2];
    const float* W2 = (const float*)d_in[3];
    const float* b2 = (const float*)d_in[4];
    float* OUT = (float*)d_out;
    short* W1P = (short*)((char*)d_ws + WS_W1P);
    short* W2P = (short*)((char*)d_ws + WS_W2P);
    short* GP  = (short*)((char*)d_ws + WS_GP);
    float* U   = (float*)((char*)d_ws + WS_U);

    k_prep<<<321, 64, 0, stream>>>(W1, W2, b2, W1P, W2P, GP, U);
    k_ode<<<1024, 256, LDS_TOTAL, stream>>>(X, W1, b1, b2, W1P, W2P, GP, U, OUT);
}

// Round 3
// 155.675 us; speedup vs baseline: 1.9265x; 1.9265x over previous
//
#include <hip/hip_runtime.h>

#define DM 1024
#define HID 64
#define NSTEP 6
#define RSTEP (1.0f/6.0f)

using short8  = __attribute__((ext_vector_type(8))) short;
using short4v = __attribute__((ext_vector_type(4))) short;
using f32x4   = __attribute__((ext_vector_type(4))) float;

// workspace byte offsets
#define WS_W1P 0          // 1024x64 bf16 packed A-frags (131072 B)
#define WS_W2P 131072     // 64x1024 bf16 packed A-frags (131072 B)
#define WS_GP  262144     // 64x64 bf16 packed A-frags (8192 B)
#define WS_U   270336     // 64 f32  (u = b2 @ W1k)

// LDS byte offsets (total 39680 B -> 4 blocks/CU on 160 KiB LDS)
#define L_ZH 0            // [16][1024] bf16 hi of z, XOR-swizzled (32768)
#define L_H0 32768        // H ping  [16][72] bf16, pitch 144 (2304)
#define L_H1 35072        // H pong
#define L_HB 37376        // Hb = (h/6)*Hsum
#define LDS_TOTAL 39680
#define HPITCH 144

// LDS-only barrier: order LDS ops, do NOT drain vmcnt (weight prefetches
// stay in flight; all cross-wave communication here is through LDS).
#define BAR() asm volatile("s_waitcnt lgkmcnt(0)\n\ts_barrier" ::: "memory")

__device__ __forceinline__ float bf2f(short s) {
    union { unsigned u; float f; } v;
    v.u = ((unsigned)(unsigned short)s) << 16;
    return v.f;
}
__device__ __forceinline__ short f2bf(float f) {   // round-to-nearest-even
    union { float f; unsigned u; } v;
    v.f = f;
    unsigned u = v.u;
    u += 0x7FFFu + ((u >> 16) & 1u);
    return (short)(u >> 16);
}
__device__ __forceinline__ float ftanh(float x) {
    x = fminf(fmaxf(x, -10.f), 10.f);
    float e = __expf(2.f * x);
    return __fdividef(e - 1.f, e + 1.f);
}

// ---------------- prep: pack weights to MFMA fragment layout ----------------
// A-frag layout for mfma_f32_16x16x32_bf16: lane l holds M-row (l&15),
// k = (l>>4)*8 + i (8 consecutive k). Packed so each lane loads one short8.
__global__ void k_prep(const float* __restrict__ W1, const float* __restrict__ W2,
                       const float* __restrict__ b2,
                       short* __restrict__ W1P, short* __restrict__ W2P,
                       short* __restrict__ GP, float* __restrict__ U) {
    __shared__ float red[4][64];
    int b = blockIdx.x;
    int t = threadIdx.x;           // 256 threads
    int l = t & 63, q4 = t >> 6;
    if (b < 128) {                 // W1k (1024x64) -> W1P[kk<32][c<4][l][8]
        if (t < 64) {
            int kk = b >> 2, c = b & 3;
            int col = c * 16 + (l & 15);
            int kb = kk * 32 + ((l >> 4) << 3);
            short8 v;
            #pragma unroll
            for (int i = 0; i < 8; ++i) v[i] = f2bf(W1[(kb + i) * HID + col]);
            *(short8*)(W1P + (((kk * 4 + c) * 64) + l) * 8) = v;
        }
    } else if (b < 256) {          // W2 (64x1024) -> W2P[kk2<2][ct<64][l][8]
        if (t < 64) {
            int bb = b - 128;
            int kk2 = bb >> 6, ct = bb & 63;
            int col = ct * 16 + (l & 15);
            int kb = kk2 * 32 + ((l >> 4) << 3);
            short8 v;
            #pragma unroll
            for (int i = 0; i < 8; ++i) v[i] = f2bf(W2[(kb + i) * DM + col]);
            *(short8*)(W2P + (((kk2 * 64 + ct) * 64) + l) * 8) = v;
        }
    } else if (b < 320) {          // G[j][i] = sum_d W2[j][d]*W1[d][i]; j = b-256
        int j = b - 256;
        float acc = 0.f;
        #pragma unroll 8
        for (int d = q4 * 256; d < q4 * 256 + 256; ++d)
            acc += W2[j * DM + d] * W1[d * HID + l];
        red[q4][l] = acc;
        __syncthreads();
        if (t < 64) {
            float a = red[0][l] + red[1][l] + red[2][l] + red[3][l];
            int kk = j >> 5, lk = (j >> 3) & 3, ii = j & 7, c = l >> 4, lo = l & 15;
            GP[(((kk * 4 + c) * 64) + lk * 16 + lo) * 8 + ii] = f2bf(a);
        }
    } else {                       // u[i] = sum_d b2[d]*W1[d][i]
        float acc = 0.f;
        #pragma unroll 8
        for (int d = q4 * 256; d < q4 * 256 + 256; ++d)
            acc += b2[d] * W1[d * HID + l];
        red[q4][l] = acc;
        __syncthreads();
        if (t < 64) U[l] = red[0][l] + red[1][l] + red[2][l] + red[3][l];
    }
}

// ---------------- fused RK4 neural-ODE kernel ----------------
// Block: 256 thr (4 waves), owns 16 rows of z for all 6 RK4 steps.
// z master = zh (bf16, LDS, swizzled) + zl (bf16 residual, REGISTERS:
// each lane owns row l15, cols [w*256 + q*16 + hq*4 + j], q=0..15).
// Wave w: GEMM1/stages hid col-tile w (16 cols); GEMM2 cols [w*256,+256).
// MFMA: A = packed weights (M = out-col), B = z/H rows (N = row).
// D: m = (lane>>4)*4+reg (col), n = lane&15 (row).
// amdgpu_waves_per_eu(2,4): stop the 8-wave occupancy heuristic from
// spilling zlr to scratch (R1/R2 post-mortem: WRITE_SIZE showed ~200 MB of
// scratch RMW at VGPR_Count=64). 4 waves/EU = the 4 blocks/CU LDS allows.
__global__ __launch_bounds__(256) __attribute__((amdgpu_waves_per_eu(2, 4)))
void k_ode(
        const float* __restrict__ X, const float* __restrict__ W1,
        const float* __restrict__ b1, const float* __restrict__ b2,
        const short* __restrict__ W1P, const short* __restrict__ W2P,
        const short* __restrict__ GP, const float* __restrict__ U,
        float* __restrict__ OUT) {
    extern __shared__ char smem[];
    const int t = threadIdx.x;
    const int lane = t & 63;
    const int w = t >> 6;                    // 0..3
    const int hq = lane >> 4;
    const int l15 = lane & 15;
    const int hcol0 = w * 16 + hq * 4;       // hid-col base (stage epilogues)
    const size_t row0 = (size_t)blockIdx.x * 16;
    const int swl = ((l15 ^ (l15 >> 3)) & 7) << 4;   // row XOR swizzle
    const int zbase = l15 << 11;                      // row byte base in zh

    // per-lane persistent constants (L2-hot broadcasts)
    f32x4 u4   = *(const f32x4*)(U + hcol0);
    f32x4 b14  = *(const f32x4*)(b1 + hcol0);
    f32x4 w1t4 = *(const f32x4*)(W1 + DM * HID + hcol0);   // time row of W1
    short8 gf0 = *(const short8*)(GP + (w * 64 + lane) * 8);
    short8 gf1 = *(const short8*)(GP + ((4 + w) * 64 + lane) * 8);

    // ---- load owned x slice -> zh (LDS) + zl (regs) ----
    short4v zlr[16];
    {
        const float* xrow = X + (row0 + l15) * DM;
        #pragma unroll
        for (int q = 0; q < 16; ++q) {
            int col = w * 256 + q * 16 + hq * 4;
            f32x4 v = *(const f32x4*)(xrow + col);
            short4v hh, ll;
            #pragma unroll
            for (int j = 0; j < 4; ++j) {
                short h = f2bf(v[j]);
                hh[j] = h;
                ll[j] = f2bf(v[j] - bf2f(h));
            }
            zlr[q] = ll;
            *(short4v*)(smem + L_ZH + ((zbase + col * 2) ^ swl)) = hh;
        }
    }
    BAR();

    for (int s = 0; s < NSTEP; ++s) {
        float tcur = RSTEP * (float)s;

        // P1: sz = (z @ W1k) tile; K=1024 in 32 slices, dual accumulators
        f32x4 sz;
        {
            const short8* wp = (const short8*)W1P + (w * 64 + lane);
            f32x4 a0 = (f32x4){0.f, 0.f, 0.f, 0.f};
            f32x4 a1 = (f32x4){0.f, 0.f, 0.f, 0.f};
            #pragma unroll 4
            for (int kk = 0; kk < 32; kk += 2) {
                short8 z0 = *(const short8*)(smem + L_ZH + ((zbase + (kk << 6) + (hq << 4)) ^ swl));
                short8 z1 = *(const short8*)(smem + L_ZH + ((zbase + ((kk + 1) << 6) + (hq << 4)) ^ swl));
                short8 wf0 = wp[kk * 256];
                short8 wf1 = wp[(kk + 1) * 256];
                a0 = __builtin_amdgcn_mfma_f32_16x16x32_bf16(wf0, z0, a0, 0, 0, 0);
                a1 = __builtin_amdgcn_mfma_f32_16x16x32_bf16(wf1, z1, a1, 0, 0, 0);
            }
            sz = a0 + a1;
        }

        // P2: stage 1  H1 = tanh(sz + t*w1t + b1)
        f32x4 hsum;
        {
            short4v hc;
            #pragma unroll
            for (int j = 0; j < 4; ++j) {
                float T = sz[j] + tcur * w1t4[j] + b14[j];
                float h = ftanh(T);
                hsum[j] = h;
                hc[j] = f2bf(h);
            }
            *(short4v*)(smem + L_H0 + l15 * HPITCH + hcol0 * 2) = hc;
        }
        BAR();

        // P3..P5: stages 2..4 via tiny H@G GEMM (G = W2@W1k)
        #pragma unroll
        for (int st = 0; st < 3; ++st) {
            const float c_i = (st == 2) ? RSTEP : (0.5f * RSTEP);
            const float t_i = tcur + ((st == 2) ? RSTEP : (0.5f * RSTEP));
            const float w_i = (st == 2) ? 1.f : 2.f;
            const int rbuf = (st & 1) ? L_H1 : L_H0;
            const int wbuf = (st & 1) ? L_H0 : L_H1;

            f32x4 dd = (f32x4){0.f, 0.f, 0.f, 0.f};
            {
                short8 hf0 = *(const short8*)(smem + rbuf + l15 * HPITCH + (hq << 4));
                short8 hf1 = *(const short8*)(smem + rbuf + l15 * HPITCH + 64 + (hq << 4));
                dd = __builtin_amdgcn_mfma_f32_16x16x32_bf16(gf0, hf0, dd, 0, 0, 0);
                dd = __builtin_amdgcn_mfma_f32_16x16x32_bf16(gf1, hf1, dd, 0, 0, 0);
            }
            short4v hc;
            #pragma unroll
            for (int j = 0; j < 4; ++j) {
                float T = sz[j] + c_i * (dd[j] + u4[j]) + t_i * w1t4[j] + b14[j];
                float h = ftanh(T);
                hsum[j] += w_i * h;
                hc[j] = f2bf(h);
            }
            if (st < 2) {
                *(short4v*)(smem + wbuf + l15 * HPITCH + hcol0 * 2) = hc;
            } else {   // Hb = (h/6) * Hsum, ready as GEMM2 B-operand
                short4v hb4;
                #pragma unroll
                for (int j = 0; j < 4; ++j) hb4[j] = f2bf(hsum[j] * (RSTEP / 6.f));
                *(short4v*)(smem + L_HB + l15 * HPITCH + hcol0 * 2) = hb4;
            }
            BAR();
        }

        // P6: z += Hb @ W2 + h*b2   (wave w owns cols [w*256, w*256+256))
        {
            short8 hb0 = *(const short8*)(smem + L_HB + l15 * HPITCH + (hq << 4));
            short8 hb1 = *(const short8*)(smem + L_HB + l15 * HPITCH + 64 + (hq << 4));
            const short8* w2p8 = (const short8*)W2P;

            if (s < NSTEP - 1) {
                #pragma unroll
                for (int q = 0; q < 16; ++q) {
                    int ct = w * 16 + q;
                    short8 wa = w2p8[ct * 64 + lane];
                    short8 wb = w2p8[(64 + ct) * 64 + lane];
                    f32x4 p = (f32x4){0.f, 0.f, 0.f, 0.f};
                    p = __builtin_amdgcn_mfma_f32_16x16x32_bf16(wa, hb0, p, 0, 0, 0);
                    p = __builtin_amdgcn_mfma_f32_16x16x32_bf16(wb, hb1, p, 0, 0, 0);
                    int colb = w * 512 + q * 32 + hq * 8;   // byte col in zh row
                    int a = (zbase + colb) ^ swl;
                    short4v oh = *(short4v*)(smem + L_ZH + a);
                    f32x4 b2v = *(const f32x4*)(b2 + (colb >> 1));
                    short4v ll = zlr[q], nh, nl;
                    #pragma unroll
                    for (int j = 0; j < 4; ++j) {
                        float v = bf2f(oh[j]) + bf2f(ll[j]) + p[j] + RSTEP * b2v[j];
                        short h = f2bf(v);
                        nh[j] = h;
                        nl[j] = f2bf(v - bf2f(h));
                    }
                    *(short4v*)(smem + L_ZH + a) = nh;
                    zlr[q] = nl;
                }
            } else {   // last step: write final z straight to OUT (f32)
                float* orow = OUT + (row0 + l15) * DM;
                #pragma unroll
                for (int q = 0; q < 16; ++q) {
                    int ct = w * 16 + q;
                    short8 wa = w2p8[ct * 64 + lane];
                    short8 wb = w2p8[(64 + ct) * 64 + lane];
                    f32x4 p = (f32x4){0.f, 0.f, 0.f, 0.f};
                    p = __builtin_amdgcn_mfma_f32_16x16x32_bf16(wa, hb0, p, 0, 0, 0);
                    p = __builtin_amdgcn_mfma_f32_16x16x32_bf16(wb, hb1, p, 0, 0, 0);
                    int colb = w * 512 + q * 32 + hq * 8;
                    int a = (zbase + colb) ^ swl;
                    short4v oh = *(short4v*)(smem + L_ZH + a);
                    f32x4 b2v = *(const f32x4*)(b2 + (colb >> 1));
                    short4v ll = zlr[q];
                    f32x4 v;
                    #pragma unroll
                    for (int j = 0; j < 4; ++j)
                        v[j] = bf2f(oh[j]) + bf2f(ll[j]) + p[j] + RSTEP * b2v[j];
                    *(f32x4*)(orow + (colb >> 1)) = v;
                }
            }
        }
        if (s < NSTEP - 1) BAR();
    }
}

extern "C" void kernel_launch(void* const* d_in, const int* in_sizes, int n_in,
                              void* d_out, int out_size, void* d_ws, size_t ws_size,
                              hipStream_t stream) {
    (void)in_sizes; (void)n_in; (void)out_size; (void)ws_size;
    const float* X  = (const float*)d_in[0];
    const float* W1 = (const float*)d_in[1];
    const float* b1 = (const float*)d_in[2];
    const float* W2 = (const float*)d_in[3];
    const float* b2 = (const float*)d_in[4];
    float* OUT = (float*)d_out;
    short* W1P = (short*)((char*)d_ws + WS_W1P);
    short* W2P = (short*)((char*)d_ws + WS_W2P);
    short* GP  = (short*)((char*)d_ws + WS_GP);
    float* U   = (float*)((char*)d_ws + WS_U);

    k_prep<<<321, 256, 0, stream>>>(W1, W2, b2, W1P, W2P, GP, U);
    k_ode<<<1024, 256, LDS_TOTAL, stream>>>(X, W1, b1, b2, W1P, W2P, GP, U, OUT);
}